// Round 9
// baseline (294.044 us; speedup 1.0000x reference)
//
#include <hip/hip_runtime.h>
#include <stdint.h>

// ReverbAugment: y[t] = sum_j h[j]*x[t-j], h[j]=rir[K-1-j] (JAX cross-corr), then /= max|y|+1e-8.
// bf16 MFMA 32x32x16. R7: Toeplitz B-dedup — Bfrag(b,j)==Bfrag(b+1,j+64), so tile-pairs at
// chunk offsets {s,s+64} give 4 MFMAs from a 2x2 outer product {A[s],A[s+64]}x{B_lo,B_hi}:
// 0.5 KB LDS per MFMA (was 1 KB). 640 blocks x 128 thr (2 waves x 4 tiles x 1024 out).

#define T_LEN   160000
#define BATCH   32
#define K_LEN   16000
#define NCHUNK_TAB 1132          // 64 zero-pad + 1002 real + 66 zero-pad chunks
#define BPR     20
#define BLK_OUT 8192             // 2 waves x 4096
#define FPAD    32               // front-pad elems: keeps final B-prefetch address >= 0
#define NST     (K_LEN + BLK_OUT + FPAD)   // 24224 staged x elems (48448 B)
#define NST8    (NST / 8)                  // 3028
#define NSTEP   1066             // ss = 0..1065  (s = ss-64 in [-64,1001])
#define LY_PITCH 33

typedef __attribute__((ext_vector_type(8)))  short short8;
typedef __attribute__((ext_vector_type(16))) float f32x16;

__device__ __forceinline__ unsigned swz(unsigned b) {   // involution on 16B slots within 128B
  return b ^ (((b >> 7) & 7u) << 4);
}

__device__ __forceinline__ short f2bf(float f) {        // RNE f32->bf16
  unsigned u = __float_as_uint(f);
  u += 0x7fffu + ((u >> 16) & 1u);
  return (short)(u >> 16);
}

__device__ __forceinline__ short8 lds_rd(const char* smem, int elem) {
  return *(const short8*)(smem + swz((unsigned)(elem * 2)));
}

// atab[jj*64+lane], j = jj-64: elem e = h[16j-16 + (lane&31) - (8*(lane>>5)+e)], h[i]=rir[K-1-i].
// Formula auto-zeroes jj<64 (all taps <0) and jj>=1066 (all taps >=K_LEN).
__global__ __launch_bounds__(256) void build_atab_k(
    const float* __restrict__ rir, short8* __restrict__ atab, unsigned* __restrict__ wsmax)
{
  int tid = blockIdx.x * 256 + threadIdx.x;
  if (tid == 0) *wsmax = 0u;
  if (tid >= NCHUNK_TAB * 64) return;
  int jj = tid >> 6, l = tid & 63;
  int m = l & 31, h = l >> 5;
  int d = 16 * (jj - 64) - 16;
  short8 o;
  #pragma unroll
  for (int e = 0; e < 8; ++e) {
    int k = d + m - (8 * h + e);
    float v = (k >= 0 && k < K_LEN) ? rir[K_LEN - 1 - k] : 0.0f;
    o[e] = f2bf(v);
  }
  atab[tid] = o;
}

__global__ __launch_bounds__(128) void conv_k(
    const float* __restrict__ x, const short8* __restrict__ atab,
    float* __restrict__ out, unsigned* __restrict__ wsmax)
{
  __shared__ __align__(16) char smem[NST * 2];   // 48448 B -> 3 blocks/CU
  __shared__ float wmaxs[2];

  int blk  = blockIdx.x;
  int brow = blk / BPR;
  int tb   = (blk - brow * BPR) * BLK_OUT;
  const float* __restrict__ xrow = x + (size_t)brow * T_LEN;
  int s_base = tb - K_LEN - FPAD;
  int tid = threadIdx.x;

  // ---- stage x[s_base .. s_base+NST) as bf16 into swizzled LDS ----
  for (int i = tid; i < NST8; i += 128) {
    int s = s_base + i * 8;
    float v[8];
    if (s >= 0 && s + 8 <= T_LEN) {
      float4 a0 = *(const float4*)(xrow + s);
      float4 a1 = *(const float4*)(xrow + s + 4);
      v[0]=a0.x; v[1]=a0.y; v[2]=a0.z; v[3]=a0.w;
      v[4]=a1.x; v[5]=a1.y; v[6]=a1.z; v[7]=a1.w;
    } else {
      #pragma unroll
      for (int e = 0; e < 8; ++e) {
        int se = s + e;
        v[e] = (se >= 0 && se < T_LEN) ? xrow[se] : 0.0f;
      }
    }
    short8 hv;
    #pragma unroll
    for (int e = 0; e < 8; ++e) hv[e] = f2bf(v[e]);
    *(short8*)(smem + swz((unsigned)(i * 16))) = hv;
  }
  __syncthreads();

  // ---- MFMA loop: wave w owns 4 tiles at tb+4096w+1024b, b=0..3 ----
  int l  = tid & 63;
  int w  = tid >> 6;
  int q  = l & 31;
  int hh = l >> 5;

  f32x16 acc0, acc1, acc2, acc3;
  #pragma unroll
  for (int r = 0; r < 16; ++r) { acc0[r]=0.f; acc1[r]=0.f; acc2[r]=0.f; acc3[r]=0.f; }

  const short8* ap = atab + l;
  // B elem for (b,j): FPAD+K_LEN+16 + 4096w + 1024b + 32q + 8hh - 16j.
  // Pair schedule (b,b+1) at j={s,s+64}, s=ss-64:  B_lo = C2-16ss (tiles 0,1), B_hi = C2+2048-16ss (2,3)
  int C2 = FPAD + K_LEN + 16 + 1024 + 4096 * w + 32 * q + 8 * hh;

  short8 aa  = ap[0];                 // A chunk jj=ss   (j=s),    feeds acc0, acc2
  short8 ab  = ap[64 * 64];           // A chunk jj=ss+64 (j=s+64), feeds acc1, acc3
  short8 blo = lds_rd(smem, C2);
  short8 bhi = lds_rd(smem, C2 + 2048);

  #pragma unroll 2
  for (int ss = 0; ss < NSTEP; ++ss) {
    short8 aan = ap[(ss + 1) * 64];          // prefetch next step (pads keep all in-bounds)
    short8 abn = ap[(ss + 65) * 64];
    int e = C2 - 16 * (ss + 1);
    short8 blon = lds_rd(smem, e);
    short8 bhin = lds_rd(smem, e + 2048);

    acc0 = __builtin_amdgcn_mfma_f32_32x32x16_bf16(aa, blo, acc0, 0, 0, 0);
    acc1 = __builtin_amdgcn_mfma_f32_32x32x16_bf16(ab, blo, acc1, 0, 0, 0);
    acc2 = __builtin_amdgcn_mfma_f32_32x32x16_bf16(aa, bhi, acc2, 0, 0, 0);
    acc3 = __builtin_amdgcn_mfma_f32_32x32x16_bf16(ab, bhi, acc3, 0, 0, 0);

    aa = aan; ab = abn; blo = blon; bhi = bhin;
  }
  __syncthreads();   // staged x no longer needed; reuse smem for D transpose

  // ---- per-wave transpose + store + max (4 tiles) ----
  float* ly = (float*)smem + w * (32 * LY_PITCH);   // 4224 B per wave
  float lm = 0.0f;
  float* __restrict__ orow = out + (size_t)brow * T_LEN;

  #pragma unroll
  for (int b = 0; b < 4; ++b) {
    f32x16 v = (b == 0) ? acc0 : (b == 1) ? acc1 : (b == 2) ? acc2 : acc3;
    #pragma unroll
    for (int r = 0; r < 16; ++r) {
      int m = (r & 3) + 8 * (r >> 2) + 4 * hh;   // D row (t mod 32)
      ly[q * LY_PITCH + m] = v[r];               // q = D col
    }
    int tbase = tb + 4096 * w + 1024 * b;
    #pragma unroll
    for (int p = 0; p < 4; ++p) {
      int t_loc = 256 * p + 4 * l;
      int t = tbase + t_loc;
      if (t < T_LEN) {
        int phys = (t_loc >> 5) * LY_PITCH + (t_loc & 31);
        float4 o4;
        o4.x = ly[phys + 0]; o4.y = ly[phys + 1]; o4.z = ly[phys + 2]; o4.w = ly[phys + 3];
        *(float4*)(orow + t) = o4;
        lm = fmaxf(lm, fmaxf(fmaxf(fabsf(o4.x), fabsf(o4.y)), fmaxf(fabsf(o4.z), fabsf(o4.w))));
      }
    }
  }

  #pragma unroll
  for (int off = 32; off; off >>= 1) lm = fmaxf(lm, __shfl_xor(lm, off));
  if (l == 0) wmaxs[w] = lm;
  __syncthreads();
  if (tid == 0) atomicMax(wsmax, __float_as_uint(fmaxf(wmaxs[0], wmaxs[1])));
}

__global__ __launch_bounds__(256) void normalize_k(
    float* __restrict__ out, const unsigned* __restrict__ wsmax, int n4)
{
  float mx = __uint_as_float(*wsmax);
  float s = 1.0f / (mx + 1e-8f);
  int stride = gridDim.x * blockDim.x;
  for (int i = blockIdx.x * blockDim.x + threadIdx.x; i < n4; i += stride) {
    float4 v = ((const float4*)out)[i];
    v.x *= s; v.y *= s; v.z *= s; v.w *= s;
    ((float4*)out)[i] = v;
  }
}

extern "C" void kernel_launch(void* const* d_in, const int* in_sizes, int n_in,
                              void* d_out, int out_size, void* d_ws, size_t ws_size,
                              hipStream_t stream) {
  const float* wav = (const float*)d_in[0];
  const float* rir = (const float*)d_in[1];
  float* outp      = (float*)d_out;
  unsigned* wsmax  = (unsigned*)d_ws;
  short8* atab     = (short8*)((char*)d_ws + 256);   // 1,159,168 B table

  hipLaunchKernelGGL(build_atab_k, dim3((NCHUNK_TAB * 64 + 255) / 256), dim3(256), 0, stream,
                     rir, atab, wsmax);
  hipLaunchKernelGGL(conv_k, dim3(BATCH * BPR), dim3(128), 0, stream,
                     wav, atab, outp, wsmax);
  hipLaunchKernelGGL(normalize_k, dim3(1280), dim3(256), 0, stream,
                     outp, wsmax, (BATCH * T_LEN) / 4);
}